// Round 7
// baseline (129.830 us; speedup 1.0000x reference)
//
#include <hip/hip_runtime.h>

// Problem constants
constexpr int cB = 64, cS = 512, cN = 512, cM = 128, cUNF = 6;
constexpr float cDELTA = 0.016666666666666666f;  // DT/UNFOLDS = 0.1/6

// Decomposition: 16 batch-groups (KB=4) x 16 j-tiles (JT=32) = 256 blocks.
// Block = 32 j-lanes x 32 i-chunks = 1024 threads; 1 block/CU, all resident.
constexpr int KB = 4;
constexpr int JT = 32;
constexpr int NJT = cN / JT;          // 16 blocks share a bg (barrier width)
constexpr int IC = 32;
constexpr int ILEN = cN / IC;         // 16
constexpr int NT = JT * IC;           // 1024
constexpr int NW = NT / 64;           // 16 waves
constexpr int NB = (cB / KB) * NJT;   // 256

// Dynamic LDS layout (floats):
//   ewl   : float2[cN*JT]  = 32768 floats (128 KB)  block's EW column slice
//   stage : float [cN*KB]  =  2048 floats (8 KB)    x / v staging [i*4+b]
//   redR  : float [KB*NW*JT] = 2048 floats (8 KB)   wave-reduced partials
//   redW  : float [KB*NW*JT] = 2048 floats (8 KB)
constexpr int SM_EW    = 0;
constexpr int SM_STAGE = cN * JT * 2;              // 32768
constexpr int SM_REDR  = SM_STAGE + cN * KB;       // 34816
constexpr int SM_REDW  = SM_REDR + KB * NW * JT;   // 36864
constexpr int SM_FLOATS = SM_REDW + KB * NW * JT;  // 38912
constexpr size_t SMEM_BYTES = (size_t)SM_FLOATS * 4;  // 155648 B = 152 KB

// ws layout (float offsets): v ping/pong + barrier counters only
constexpr size_t OFF_VA  = 0;
constexpr size_t OFF_VB  = OFF_VA + (size_t)cB * cN;
constexpr size_t OFF_CTR = OFF_VB + (size_t)cB * cN;   // int[bg*16], 64B-spaced
constexpr int CTR_INTS = 16 * 16;

__device__ __forceinline__ float clamp01(float x) {
    return __builtin_amdgcn_fmed3f(x, 0.0f, 1.0f);
}

// ---- k_sns: one dispatch, everything block-local except the v exchange.
//  Phase A: EW column slice -> LDS (once) + block-local gate-uniformity probe
//  Phase B: sensory reduction (wave shfl pre-reduce -> 16KB LDS -> owner regs)
//  Phase C: 6 unfolds; inner loop is LDS-only; v exchanged via sc1 atomics;
//           per-bg 16-way relaxed monotonic barriers (64B-spaced lines).
__global__ __launch_bounds__(NT)
void k_sns(const float* __restrict__ inputs, const float* __restrict__ states,
           const float* __restrict__ tau,    const float* __restrict__ bias,
           const float* __restrict__ erev,   const float* __restrict__ wgt,
           const float* __restrict__ sigma,  const float* __restrict__ mu,
           const float* __restrict__ serev,  const float* __restrict__ swgt,
           const float* __restrict__ ssigma, const float* __restrict__ smu,
           const float* __restrict__ mask,   const float* __restrict__ smask,
           const float* __restrict__ inw,    const float* __restrict__ inb,
           const float* __restrict__ outw,   const float* __restrict__ outb,
           float* __restrict__ out, float* __restrict__ ws)
{
    extern __shared__ float smem[];
    float2* ewl  = (float2*)(smem + SM_EW);
    float*  stage = smem + SM_STAGE;
    float*  redR  = smem + SM_REDR;
    float*  redW  = smem + SM_REDW;

    float* vA  = ws + OFF_VA;
    float* vB  = ws + OFF_VB;
    int*   ctr = (int*)(ws + OFF_CTR);

    const int tid = threadIdx.x, bid = blockIdx.x;
    // XCD swizzle (perf heuristic only): blocks sharing a jt get bid%8 const.
    const int jt = (bid & 7) * 2 + ((bid >> 3) & 1);
    const int bg = bid >> 4;
    const int b0 = bg * KB, j0 = jt * JT;
    const int jl = tid & (JT - 1), ic = tid >> 5;
    const int wv_id = tid >> 6, lane = tid & 63;
    const int j = j0 + jl;
    int* barU = ctr + bg * 16;          // per-bg 64B-spaced barrier line

    // ---- Phase A: EW slice -> LDS + block-local uniformity probe ----
    int ok = 1;
    {
        int idx = (ic * ILEN) * cN + j;     // i = ic*16+ii, col j
        int eo  = (ic * ILEN) * JT + jl;
#pragma unroll 4
        for (int ii = 0; ii < ILEN; ++ii, idx += cN, eo += JT) {
            float mk = mask[idx];
            ewl[eo] = make_float2(erev[idx] * mk, wgt[idx] * mk);
            ok &= (sigma[idx] == 0.5f) & (mu[idx] == 0.5f);
        }
    }

    // ---- Phase B: sensory reduction ----
#pragma unroll
    for (int r = 0; r < (cS * KB) / NT; ++r) {
        int t = tid + r * NT;
        int bb = t & 3, s = t >> 2;
        stage[t] = fmaf(inputs[(b0 + bb) * cS + s], inw[s], inb[s]);
    }
    const int fast = __syncthreads_and(ok);   // barrier: ewl + stage(x) ready
    {
        float aR[KB] = {0.f, 0.f, 0.f, 0.f}, aW[KB] = {0.f, 0.f, 0.f, 0.f};
        int idx = (ic * ILEN) * cN + j;
        int xo  = (ic * ILEN) * KB;
#pragma unroll 4
        for (int ii = 0; ii < ILEN; ++ii, idx += cN, xo += KB) {
            float sg = ssigma[idx];
            float a  = 0.5f / sg;
            float c  = fmaf(-smu[idx], a, 0.5f);
            float mk = smask[idx];
            float e  = serev[idx] * mk;
            float wvv = swgt[idx] * mk;
            const float4 xv = *(const float4*)&stage[xo];
            float g;
            g = clamp01(fmaf(xv.x, a, c)); aR[0] = fmaf(g, e, aR[0]); aW[0] = fmaf(g, wvv, aW[0]);
            g = clamp01(fmaf(xv.y, a, c)); aR[1] = fmaf(g, e, aR[1]); aW[1] = fmaf(g, wvv, aW[1]);
            g = clamp01(fmaf(xv.z, a, c)); aR[2] = fmaf(g, e, aR[2]); aW[2] = fmaf(g, wvv, aW[2]);
            g = clamp01(fmaf(xv.w, a, c)); aR[3] = fmaf(g, e, aR[3]); aW[3] = fmaf(g, wvv, aW[3]);
        }
        // wave pre-reduce: combine the wave's two i-chunks (lanes ^32)
#pragma unroll
        for (int b = 0; b < KB; ++b) {
            aR[b] += __shfl_xor(aR[b], 32, 64);
            aW[b] += __shfl_xor(aW[b], 32, 64);
        }
        if (lane < JT) {
#pragma unroll
            for (int b = 0; b < KB; ++b) {
                redR[(b * NW + wv_id) * JT + jl] = aR[b];
                redW[(b * NW + wv_id) * JT + jl] = aW[b];
            }
        }
    }
    __syncthreads();

    // owner threads (tid < 128) finish sensory reduction -> registers only
    float my_srb = 0.f, my_sw = 0.f, my_tau = 0.f, my_ow = 0.f, my_ob = 0.f;
    int my_gidx = 0, my_mi = -1;
    if (tid < JT * KB) {
        int jj = tid & (JT - 1), bb = tid >> 5;
        float r = 0.f, wvv = 0.f;
#pragma unroll
        for (int w = 0; w < NW; ++w) {
            r   += redR[(bb * NW + w) * JT + jj];
            wvv += redW[(bb * NW + w) * JT + jj];
        }
        int jg  = j0 + jj;
        my_gidx = (b0 + bb) * cN + jg;
        my_srb  = r + bias[jg];    // s_rev + b folded
        my_sw   = wvv;
        my_tau  = tau[jg];
        if (jg >= cN - cM) {
            int m = jg - (cN - cM);
            my_ow = outw[m]; my_ob = outb[m];
            my_mi = (b0 + bb) * cM + m;
        }
    }

    // ---- Phase C: 6 unfolds ----
    const float* vin = states;
    for (int u = 0; u < cUNF; ++u) {
        float* vout = (u == cUNF - 1) ? (out + cB * cM) : ((u & 1) ? vA : vB);

        // stage v (sc1 loads: always-fresh, bypass stale per-XCD L2)
#pragma unroll
        for (int r = 0; r < (cN * KB) / NT; ++r) {   // 2 per thread
            int t = tid + r * NT;
            int bb = t & 3, ii = t >> 2;
            float vvv = __hip_atomic_load(&vin[(b0 + bb) * cN + ii],
                                          __ATOMIC_RELAXED, __HIP_MEMORY_SCOPE_AGENT);
            stage[t] = fast ? clamp01(vvv) : vvv;
        }
        __syncthreads();

        float vold = 0.f;
        if (tid < JT * KB)
            vold = __hip_atomic_load(&vin[my_gidx],
                                     __ATOMIC_RELAXED, __HIP_MEMORY_SCOPE_AGENT);

        float aR[KB] = {0.f, 0.f, 0.f, 0.f}, aW[KB] = {0.f, 0.f, 0.f, 0.f};
        if (fast) {
            // LDS-only inner loop: ds_read_b64 (EW) + ds_read_b128 (v bcast) + 8 fma
            int eo = (ic * ILEN) * JT + jl;
            int vo = (ic * ILEN) * KB;
#pragma unroll
            for (int ii = 0; ii < ILEN; ++ii, eo += JT, vo += KB) {
                const float2 ew = ewl[eo];
                const float4 g4 = *(const float4*)&stage[vo];
                aR[0] = fmaf(g4.x, ew.x, aR[0]); aW[0] = fmaf(g4.x, ew.y, aW[0]);
                aR[1] = fmaf(g4.y, ew.x, aR[1]); aW[1] = fmaf(g4.y, ew.y, aW[1]);
                aR[2] = fmaf(g4.z, ew.x, aR[2]); aW[2] = fmaf(g4.z, ew.y, aW[2]);
                aR[3] = fmaf(g4.w, ew.x, aR[3]); aW[3] = fmaf(g4.w, ew.y, aW[3]);
            }
        } else {
            // general gate path: a,c recomputed from global sigma/mu (L2-served)
            int idx = (ic * ILEN) * cN + j;
            int eo  = (ic * ILEN) * JT + jl;
            int vo  = (ic * ILEN) * KB;
#pragma unroll 4
            for (int ii = 0; ii < ILEN; ++ii, idx += cN, eo += JT, vo += KB) {
                float sg = sigma[idx];
                float a  = 0.5f / sg;
                float c  = fmaf(-mu[idx], a, 0.5f);
                const float2 ew = ewl[eo];
                const float4 vv4 = *(const float4*)&stage[vo];
                float g;
                g = clamp01(fmaf(vv4.x, a, c)); aR[0] = fmaf(g, ew.x, aR[0]); aW[0] = fmaf(g, ew.y, aW[0]);
                g = clamp01(fmaf(vv4.y, a, c)); aR[1] = fmaf(g, ew.x, aR[1]); aW[1] = fmaf(g, ew.y, aW[1]);
                g = clamp01(fmaf(vv4.z, a, c)); aR[2] = fmaf(g, ew.x, aR[2]); aW[2] = fmaf(g, ew.y, aW[2]);
                g = clamp01(fmaf(vv4.w, a, c)); aR[3] = fmaf(g, ew.x, aR[3]); aW[3] = fmaf(g, ew.y, aW[3]);
            }
        }
        // wave pre-reduce, then 16KB LDS
#pragma unroll
        for (int b = 0; b < KB; ++b) {
            aR[b] += __shfl_xor(aR[b], 32, 64);
            aW[b] += __shfl_xor(aW[b], 32, 64);
        }
        if (lane < JT) {
#pragma unroll
            for (int b = 0; b < KB; ++b) {
                redR[(b * NW + wv_id) * JT + jl] = aR[b];
                redW[(b * NW + wv_id) * JT + jl] = aW[b];
            }
        }
        __syncthreads();

        if (tid < JT * KB) {
            int jj = tid & (JT - 1), bb = tid >> 5;
            float r = 0.f, wvv = 0.f;
#pragma unroll
            for (int w = 0; w < NW; ++w) {
                r   += redR[(bb * NW + w) * JT + jj];
                wvv += redW[(bb * NW + w) * JT + jj];
            }
            r   += my_srb;
            wvv += my_sw;
            float k    = 1.0f / (1.0f + wvv);
            float taun = my_tau * k;
            float inv  = 1.0f / (taun + cDELTA);
            float vn   = (taun * inv) * vold + (cDELTA * inv) * k * r;
            if (u == cUNF - 1) {
                vout[my_gidx] = vn;                       // plain: dispatch-end flush
                if (my_mi >= 0) out[my_mi] = fmaf(vn, my_ow, my_ob);
            } else {
                __hip_atomic_store(&vout[my_gidx], vn,
                                   __ATOMIC_RELAXED, __HIP_MEMORY_SCOPE_AGENT);
            }
        }

        if (u < cUNF - 1) {
            __syncthreads();   // vmcnt(0) drain: block's sc1 v-stores at coherence point
            if (tid == 0) {
                __hip_atomic_fetch_add(barU, 1, __ATOMIC_RELAXED, __HIP_MEMORY_SCOPE_AGENT);
                const int target = NJT * (u + 1);   // monotonic counter
                while (__hip_atomic_load(barU, __ATOMIC_RELAXED, __HIP_MEMORY_SCOPE_AGENT) < target)
                    __builtin_amdgcn_s_sleep(1);
            }
            __syncthreads();
            vin = (u & 1) ? vA : vB;   // buffer just produced
        }
    }
}

extern "C" void kernel_launch(void* const* d_in, const int* in_sizes, int n_in,
                              void* d_out, int out_size, void* d_ws, size_t ws_size,
                              hipStream_t stream)
{
    const float* inputs = (const float*)d_in[0];
    const float* states = (const float*)d_in[1];
    const float* tau    = (const float*)d_in[2];
    const float* bias   = (const float*)d_in[3];
    const float* erev   = (const float*)d_in[4];
    const float* wgt    = (const float*)d_in[5];
    const float* sigma  = (const float*)d_in[6];
    const float* mu     = (const float*)d_in[7];
    const float* serev  = (const float*)d_in[8];
    const float* swgt   = (const float*)d_in[9];
    const float* ssigma = (const float*)d_in[10];
    const float* smu    = (const float*)d_in[11];
    const float* mask   = (const float*)d_in[12];
    const float* smask  = (const float*)d_in[13];
    const float* inw    = (const float*)d_in[14];
    const float* inb    = (const float*)d_in[15];
    const float* outw   = (const float*)d_in[16];
    const float* outb   = (const float*)d_in[17];
    float* out = (float*)d_out;
    float* ws  = (float*)d_ws;

    // allow 152 KB dynamic LDS (gfx950: 160 KiB/CU); idempotent, capture-safe
    hipFuncSetAttribute((const void*)k_sns,
                        hipFuncAttributeMaxDynamicSharedMemorySize,
                        (int)SMEM_BYTES);

    // zero per-bg barrier counters (16 x 64B)
    hipMemsetAsync(ws + OFF_CTR, 0, CTR_INTS * sizeof(int), stream);

    // single fused dispatch: 256 blocks x 1024 threads = 1 block/CU, all
    // co-resident -> internal spin barriers cannot deadlock.
    k_sns<<<NB, NT, SMEM_BYTES, stream>>>(inputs, states, tau, bias, erev, wgt,
                                          sigma, mu, serev, swgt, ssigma, smu,
                                          mask, smask, inw, inb, outw, outb,
                                          out, ws);
}